// Round 16
// baseline (602.933 us; speedup 1.0000x reference)
//
#include <hip/hip_runtime.h>
#include <hip/hip_bf16.h>
#include <cstdint>
#include <cstddef>

#define VOCAB 50001
#define EMB 64
#define HID 128
#define G4  512   // 4*HID
#define TAGS 32
#define BATCH 256
#define SEQ 512

typedef _Float16 f16;
typedef _Float16 f16x2 __attribute__((ext_vector_type(2)));
typedef _Float16 f16x4 __attribute__((ext_vector_type(4)));
typedef _Float16 f16x8 __attribute__((ext_vector_type(8)));
typedef float f32x4 __attribute__((ext_vector_type(4)));

__device__ __forceinline__ float rcpf(float x) { return __builtin_amdgcn_rcpf(x); }
__device__ __forceinline__ float rfl(float x) {
  return __builtin_bit_cast(float, __builtin_amdgcn_readfirstlane(__builtin_bit_cast(int, x)));
}

#define MFMA16(A, B, C) __builtin_amdgcn_mfma_f32_16x16x32_f16((A), (B), (C), 0, 0, 0)

// ---------------------------------------------------------------------------
// Kernel A: gate tables via MFMA. G[v][hid*4+gate] = (E @ Wk + b), f16.
// Merged n0 tiles: stage E once per 64-row block, loop over both gate-pairs
// (halves E fetch + block count vs split version).
// ---------------------------------------------------------------------------
__global__ __launch_bounds__(256)
void gtab_mfma_kernel(const float* __restrict__ E,
                      const float* __restrict__ Wk_f, const float* __restrict__ b_f,
                      const float* __restrict__ Wk_b, const float* __restrict__ b_b,
                      f16* __restrict__ G_f, f16* __restrict__ G_b) {
  const int dir = blockIdx.z;
  const float* __restrict__ Wk   = dir ? Wk_b : Wk_f;
  const float* __restrict__ bias = dir ? b_b  : b_f;
  f16* __restrict__ G = dir ? G_b : G_f;

  const int m0 = blockIdx.x * 64;
  const int tid = threadIdx.x;

  __shared__ f16 Eh[64][80];
  __shared__ f16 Bh[256][80];

  #pragma unroll
  for (int s = 0; s < 4; ++s) {
    int idx = tid + s * 256;
    int r = idx >> 4, c4 = (idx & 15) * 4;
    int row = m0 + r;
    float4 ev;
    if (row < VOCAB) ev = *(const float4*)(E + (size_t)row * EMB + c4);
    else { ev.x = 0.f; ev.y = 0.f; ev.z = 0.f; ev.w = 0.f; }
    f16x4 v; v[0] = (f16)ev.x; v[1] = (f16)ev.y; v[2] = (f16)ev.z; v[3] = (f16)ev.w;
    *(f16x4*)&Eh[r][c4] = v;
  }

  const int w = tid >> 6, l = tid & 63, mn = l & 15, q = l >> 4;
  f16x8 a0, a1;
  bool afrag_loaded = false;

  for (int np = 0; np < 2; ++np) {
    const int n0 = np * 256;
    // stage Bh[n][k] = Wk[k][n0+n]
    #pragma unroll
    for (int s = 0; s < 32; ++s) {
      int idx = tid + s * 256;
      int k = idx >> 7, n2 = (idx & 127) * 2;
      float2 wv = *(const float2*)(Wk + (size_t)k * G4 + n0 + n2);
      Bh[n2][k]     = (f16)wv.x;
      Bh[n2 + 1][k] = (f16)wv.y;
    }
    __syncthreads();

    if (!afrag_loaded) {
      a0 = *(const f16x8*)&Eh[16 * w + mn][8 * q];
      a1 = *(const f16x8*)&Eh[16 * w + mn][32 + 8 * q];
      afrag_loaded = true;
    }

    f32x4 acc[16];
    #pragma unroll
    for (int nt = 0; nt < 16; ++nt) {
      f16x8 b0 = *(const f16x8*)&Bh[16 * nt + mn][8 * q];
      f16x8 b1 = *(const f16x8*)&Bh[16 * nt + mn][32 + 8 * q];
      f32x4 z = {0.f, 0.f, 0.f, 0.f};
      z = MFMA16(a0, b0, z);
      z = MFMA16(a1, b1, z);
      acc[nt] = z;
    }

    const int gA = n0 >> 7;   // 0 or 2
    #pragma unroll
    for (int nt = 0; nt < 8; ++nt) {
      int hid = 16 * nt + mn;
      float bv0 = bias[n0 + 16 * nt + mn];
      float bv1 = bias[n0 + 128 + 16 * nt + mn];
      #pragma unroll
      for (int reg = 0; reg < 4; ++reg) {
        int row = m0 + 16 * w + 4 * q + reg;
        if (row < VOCAB) {
          f16x2 v; v.x = (f16)(acc[nt][reg] + bv0); v.y = (f16)(acc[nt + 8][reg] + bv1);
          *(f16x2*)(G + (size_t)row * G4 + hid * 4 + gA) = v;
        }
      }
    }
    __syncthreads();   // before Bh restage (no-op cost on last iter)
  }
}

// ---------------------------------------------------------------------------
// Kernel B: MFMA LSTM, broadcast-A: 4 batches per block, A[m][k]=h[m&3][k]
// so D row r = batch r&3 — every lane holds z for all 4 batches in C-regs.
// 128 blocks (64 bg x 2 dir), 512 thr. Wave w owns gate cols {128g+16w+mn};
// 16 MFMA/wave/step serve 4 chains. Gates: ALL 512 threads, lane (q,mn)
// selects batch=q via cndmask from regs, 1 gate-set each, writes h.
// ONE lgkm-only barrier/step (h dbuf). G prefetch ring depth 4.
// Logit MFMAs on waves 6,7 with incremental store pointer.
// ---------------------------------------------------------------------------
__global__ __launch_bounds__(512, 1)
void lstm_mfma_kernel(const int* __restrict__ tokens,
                      const f16* __restrict__ G_f, const f16* __restrict__ G_b,
                      const float* __restrict__ Wr_f, const float* __restrict__ Wr_b,
                      const float* __restrict__ Wd, const float* __restrict__ bd,
                      float* __restrict__ Lf, float* __restrict__ Lb) {
  const int bg  = blockIdx.x;          // 0..63
  const int dir = blockIdx.y;
  const int b0  = bg * 4;
  const f16* __restrict__ G = dir ? G_b : G_f;
  const char* __restrict__ Gc = (const char*)G;
  const float* __restrict__ Wr = dir ? Wr_b : Wr_f;
  float* __restrict__ Lout = dir ? Lb : Lf;

  const int tid = threadIdx.x;
  const int w = tid >> 6;
  const int l = tid & 63;
  const int mn = l & 15;
  const int q  = l >> 4;
  const int hid = 16 * w + mn;
  const int hid8 = hid * 8;            // byte offset: hid*4 f16

  __shared__ __align__(16) f16 h_lds[2][4][160];   // [buf][batch][hid+pad]
  __shared__ int tokT[SEQ][4];                     // pre-shifted byte offsets

  #pragma unroll
  for (int s = 0; s < 4; ++s) {
    int idx = tid + s * 512;            // 2048 entries
    int t = idx >> 2, qq = idx & 3;
    tokT[t][qq] = tokens[(size_t)(b0 + qq) * SEQ + t] << 10;
  }
  if (tid < 320) ((unsigned*)&h_lds[0][0][0])[tid] = 0u;   // zero buf 0

  // B fragments: Wr[k][128g + hid], k = 32s + 8q + j  (64 VGPRs)
  f16x8 bw[4][4];
  #pragma unroll
  for (int g = 0; g < 4; ++g) {
    #pragma unroll
    for (int s = 0; s < 4; ++s) {
      f16x8 v;
      const int colv = 128 * g + hid;
      #pragma unroll
      for (int j = 0; j < 8; ++j)
        v[j] = (f16)Wr[(size_t)(32 * s + 8 * q + j) * G4 + colv];
      bw[g][s] = v;
    }
  }
  // Wd fragments on waves 6,7: tag = 16*(w-6)+mn
  f16x8 wdf0{}, wdf1{}, wdf2{}, wdf3{};
  float bdv = 0.0f;
  if (w >= 6) {
    const int tag = 16 * (w - 6) + mn;
    #pragma unroll
    for (int j = 0; j < 8; ++j) {
      wdf0[j] = (f16)Wd[(size_t)(128 * dir +  0 + 8 * q + j) * TAGS + tag];
      wdf1[j] = (f16)Wd[(size_t)(128 * dir + 32 + 8 * q + j) * TAGS + tag];
      wdf2[j] = (f16)Wd[(size_t)(128 * dir + 64 + 8 * q + j) * TAGS + tag];
      wdf3[j] = (f16)Wd[(size_t)(128 * dir + 96 + 8 * q + j) * TAGS + tag];
    }
    if (dir == 0) bdv = bd[tag];
  }

  // incremental logit store pointer (waves 6,7 / q==0 use it)
  const int t0 = dir ? (SEQ - 1) : 0;
  const int tagw = (w >= 6) ? (16 * (w - 6) + mn) : 0;
  char* lp = (char*)(Lout + ((size_t)b0 * SEQ + t0) * TAGS + tagw);
  const int ldt = dir ? -(int)(TAGS * 4) : (int)(TAGS * 4);

  float cst = 0.0f;   // cell state for (batch q, hid) — every lane
  __syncthreads();

#define TT(S) (dir ? (SEQ - 1 - (S)) : (S))

#define LOADG(S, GV) do {                                                      \
    int _tk = tokT[TT(S)][q];                                                  \
    GV = *(const uint2*)(Gc + _tk + hid8);                                     \
  } while (0)

// select element `q` (lane-var) from the 4 accum rows (= batches)
#define SEL4(V) ((q & 2) ? ((q & 1) ? V[3] : V[2]) : ((q & 1) ? V[1] : V[0]))

#define STEP(S, GV) do {                                                       \
    const int _s = (S);                                                        \
    const f16* hb = &h_lds[_s & 1][mn & 3][0];                                 \
    f16x8 a0 = *(const f16x8*)(hb      + 8 * q);                               \
    f16x8 a1 = *(const f16x8*)(hb + 32 + 8 * q);                               \
    f16x8 a2 = *(const f16x8*)(hb + 64 + 8 * q);                               \
    f16x8 a3 = *(const f16x8*)(hb + 96 + 8 * q);                               \
    f32x4 z0 = {0.f,0.f,0.f,0.f}, z1 = {0.f,0.f,0.f,0.f};                      \
    f32x4 z2 = {0.f,0.f,0.f,0.f}, z3 = {0.f,0.f,0.f,0.f};                      \
    z0 = MFMA16(a0, bw[0][0], z0); z0 = MFMA16(a1, bw[0][1], z0);              \
    z0 = MFMA16(a2, bw[0][2], z0); z0 = MFMA16(a3, bw[0][3], z0);              \
    z1 = MFMA16(a0, bw[1][0], z1); z1 = MFMA16(a1, bw[1][1], z1);              \
    z1 = MFMA16(a2, bw[1][2], z1); z1 = MFMA16(a3, bw[1][3], z1);              \
    z2 = MFMA16(a0, bw[2][0], z2); z2 = MFMA16(a1, bw[2][1], z2);              \
    z2 = MFMA16(a2, bw[2][2], z2); z2 = MFMA16(a3, bw[2][3], z2);              \
    z3 = MFMA16(a0, bw[3][0], z3); z3 = MFMA16(a1, bw[3][1], z3);              \
    z3 = MFMA16(a2, bw[3][2], z3); z3 = MFMA16(a3, bw[3][3], z3);              \
    if (w >= 6) {                                                              \
      f32x4 la = {0.f,0.f,0.f,0.f};                                            \
      la = MFMA16(a0, wdf0, la); la = MFMA16(a1, wdf1, la);                    \
      la = MFMA16(a2, wdf2, la); la = MFMA16(a3, wdf3, la);                    \
      if (q == 0) {                                                            \
        *(float*)(lp               ) = la[0] + bdv;                            \
        *(float*)(lp + SEQ*TAGS*4  ) = la[1] + bdv;                            \
        *(float*)(lp + SEQ*TAGS*8  ) = la[2] + bdv;                            \
        *(float*)(lp + SEQ*TAGS*12 ) = la[3] + bdv;                            \
      }                                                                        \
    }                                                                          \
    lp += ldt;                                                                 \
    {                                                                          \
      float zi = SEL4(z0);                                                     \
      float zf = SEL4(z1);                                                     \
      float zg = SEL4(z2);                                                     \
      float zo = SEL4(z3);                                                     \
      f16x4 gv = __builtin_bit_cast(f16x4, GV);                                \
      zi += (float)gv[0]; zf += (float)gv[1];                                  \
      zg += (float)gv[2]; zo += (float)gv[3];                                  \
      float ei = __expf(-zi);                                                  \
      float eg = __expf(fminf(2.f * zg, 30.f));                                \
      float sab = (eg - 1.f) * rcpf((1.f + ei) * (eg + 1.f));                  \
      float ef = __expf(-zf);                                                  \
      float cc = rcpf(1.f + ef) * cst + sab;                                   \
      cst = cc;                                                                \
      float eo = __expf(-zo);                                                  \
      float ec = __expf(fminf(2.f * cc, 30.f));                                \
      float hh = (ec - 1.f) * rcpf((1.f + eo) * (ec + 1.f));                   \
      h_lds[(_s + 1) & 1][q][hid] = (f16)hh;                                   \
    }                                                                          \
    asm volatile("s_waitcnt lgkmcnt(0)" ::: "memory");                         \
    __builtin_amdgcn_s_barrier();                                              \
  } while (0)

  uint2 gA, gB, gC, gD;
  LOADG(0, gA); LOADG(1, gB); LOADG(2, gC); LOADG(3, gD);

  for (int it = 0; it < SEQ / 4; ++it) {
    const int s = 4 * it;
    STEP(s + 0, gA);
    { int sc = (s + 4 < SEQ) ? s + 4 : SEQ - 1; LOADG(sc, gA); }
    STEP(s + 1, gB);
    { int sc = (s + 5 < SEQ) ? s + 5 : SEQ - 1; LOADG(sc, gB); }
    STEP(s + 2, gC);
    { int sc = (s + 6 < SEQ) ? s + 6 : SEQ - 1; LOADG(sc, gC); }
    STEP(s + 3, gD);
    { int sc = (s + 7 < SEQ) ? s + 7 : SEQ - 1; LOADG(sc, gD); }
  }
#undef STEP
#undef SEL4
#undef LOADG
#undef TT
}

// ---------------------------------------------------------------------------
// Kernel C: CRF log-likelihood. ONE wave per batch, 256 blocks. Factorized
// exp-space scan; renorm every 4 steps (beta stays < ~40, e^beta f32-safe);
// incremental L pointer.
// ---------------------------------------------------------------------------
__global__ __launch_bounds__(64)
void crf_kernel(const float* __restrict__ Lf,
                const float* __restrict__ Lb,
                const float* __restrict__ trans,
                const int* __restrict__ labels,
                float* __restrict__ out) {
  const int b = blockIdx.x;
  const int lane = threadIdx.x;
  const int k  = lane & 31;
  const int jh = lane >> 5;

  __shared__ float tr[TAGS * TAGS];
  __shared__ __align__(16) float e_lds[TAGS];

  for (int i = lane; i < TAGS * TAGS; i += 64) tr[i] = trans[i];
  __syncthreads();

  float wxp[16];
  #pragma unroll
  for (int i = 0; i < 16; ++i) wxp[i] = __expf(tr[(jh * 16 + i) * TAGS + k]);

  const size_t base0 = (size_t)b * SEQ * TAGS;
  float cur = Lf[base0 + k] + Lb[base0 + k];
  float beta0 = rfl(cur);
  float beta = cur - beta0;
  float S = beta0;

  const float* lfp = Lf + base0 + TAGS + k;
  const float* lbp = Lb + base0 + TAGS + k;
  float nxt = *lfp + *lbp;

  for (int t = 1; t < SEQ; ++t) {
    float e = __expf(beta);
    if (lane < TAGS) e_lds[k] = e;
    asm volatile("s_waitcnt lgkmcnt(0)" ::: "memory");
    const float4* ep = (const float4*)&e_lds[jh * 16];
    float4 e0 = ep[0], e1 = ep[1], e2 = ep[2], e3 = ep[3];
    float d0 = e0.x * wxp[0]  + e0.y * wxp[1]  + e0.z * wxp[2]  + e0.w * wxp[3];
    float d1 = e1.x * wxp[4]  + e1.y * wxp[5]  + e1.z * wxp[6]  + e1.w * wxp[7];
    float d2 = e2.x * wxp[8]  + e2.y * wxp[9]  + e2.z * wxp[10] + e2.w * wxp[11];
    float d3 = e3.x * wxp[12] + e3.y * wxp[13] + e3.z * wxp[14] + e3.w * wxp[15];
    float dot = (d0 + d1) + (d2 + d3);
    dot += __shfl_xor(dot, 32);
    float braw = __logf(dot) + nxt;
    if ((t & 3) == 0) {
      float bz = rfl(braw);
      beta = braw - bz;
      S += bz;
    } else {
      beta = braw;
    }
    if (t + 1 < SEQ) {
      lfp += TAGS; lbp += TAGS;
      nxt = *lfp + *lbp;
    }
  }

  float m = beta;
  #pragma unroll
  for (int off = 1; off <= 16; off <<= 1) m = fmaxf(m, __shfl_xor(m, off));
  float ex = (lane < TAGS) ? __expf(beta - m) : 0.0f;
  float s = ex;
  #pragma unroll
  for (int off = 1; off <= 32; off <<= 1) s += __shfl_xor(s, off);

  const int* lab = labels + (size_t)b * SEQ;
  float uacc = 0.f, bacc = 0.f;
  for (int t = lane; t < SEQ; t += 64) {
    int l0 = lab[t];
    size_t idx = base0 + (size_t)t * TAGS + l0;
    uacc += Lf[idx] + Lb[idx];
    if (t + 1 < SEQ) bacc += tr[l0 * TAGS + lab[t + 1]];
  }
  float red = uacc + bacc;
  #pragma unroll
  for (int off = 1; off <= 32; off <<= 1) red += __shfl_xor(red, off);

  if (lane == 0) out[b] = red - (m + __logf(s) + S);
}

// ---------------------------------------------------------------------------
// Kernel D: copy transition matrix to the second output slot.
// ---------------------------------------------------------------------------
__global__ void copy_trans_kernel(const float* __restrict__ trans,
                                  float* __restrict__ out) {
  int i = blockIdx.x * blockDim.x + threadIdx.x;
  if (i < TAGS * TAGS) out[i] = trans[i];
}

extern "C" void kernel_launch(void* const* d_in, const int* in_sizes, int n_in,
                              void* d_out, int out_size, void* d_ws, size_t ws_size,
                              hipStream_t stream) {
  const int*   inputs = (const int*)  d_in[0];
  const int*   labels = (const int*)  d_in[1];
  const float* E      = (const float*)d_in[2];
  const float* Wk_f   = (const float*)d_in[3];
  const float* Wr_f   = (const float*)d_in[4];
  const float* b_f    = (const float*)d_in[5];
  const float* Wk_b   = (const float*)d_in[6];
  const float* Wr_b   = (const float*)d_in[7];
  const float* b_b    = (const float*)d_in[8];
  const float* Wd     = (const float*)d_in[9];
  const float* bd     = (const float*)d_in[10];
  const float* trans  = (const float*)d_in[11];
  float* out = (float*)d_out;

  char* ws = (char*)d_ws;
  const size_t G_ELEMS = (size_t)VOCAB * G4;            // 25,600,512 f16 each dir
  f16* G_f = (f16*)ws;
  f16* G_b = G_f + G_ELEMS;
  float* Lfp = (float*)(ws + 2 * G_ELEMS * sizeof(f16));
  float* Lbp = Lfp + (size_t)BATCH * SEQ * TAGS;

  dim3 ggrid((VOCAB + 63) / 64, 1, 2);
  gtab_mfma_kernel<<<ggrid, 256, 0, stream>>>(E, Wk_f, b_f, Wk_b, b_b, G_f, G_b);

  lstm_mfma_kernel<<<dim3(BATCH / 4, 2), 512, 0, stream>>>(
      inputs, G_f, G_b, Wr_f, Wr_b, Wd, bd, Lfp, Lbp);

  crf_kernel<<<BATCH, 64, 0, stream>>>(Lfp, Lbp, trans, labels, out);

  copy_trans_kernel<<<(TAGS * TAGS + 255) / 256, 256, 0, stream>>>(trans, out + BATCH);
}

// Round 17
// 499.424 us; speedup vs baseline: 1.2073x; 1.2073x over previous
//
#include <hip/hip_runtime.h>
#include <hip/hip_bf16.h>
#include <cstdint>
#include <cstddef>

#define VOCAB 50001
#define EMB 64
#define HID 128
#define G4  512   // 4*HID
#define TAGS 32
#define BATCH 256
#define SEQ 512

typedef _Float16 f16;
typedef _Float16 f16x2 __attribute__((ext_vector_type(2)));
typedef _Float16 f16x4 __attribute__((ext_vector_type(4)));
typedef _Float16 f16x8 __attribute__((ext_vector_type(8)));
typedef float f32x4 __attribute__((ext_vector_type(4)));

__device__ __forceinline__ float rcpf(float x) { return __builtin_amdgcn_rcpf(x); }
__device__ __forceinline__ float rfl(float x) {
  return __builtin_bit_cast(float, __builtin_amdgcn_readfirstlane(__builtin_bit_cast(int, x)));
}

#define MFMA16(A, B, C) __builtin_amdgcn_mfma_f32_16x16x32_f16((A), (B), (C), 0, 0, 0)

// ---------------------------------------------------------------------------
// Kernel A: gate tables via MFMA (R15 split form — measured best).
// G[v][hid*4+gate] = (E @ Wk + b), f16, gate-interleaved.
// ---------------------------------------------------------------------------
__global__ __launch_bounds__(256)
void gtab_mfma_kernel(const float* __restrict__ E,
                      const float* __restrict__ Wk_f, const float* __restrict__ b_f,
                      const float* __restrict__ Wk_b, const float* __restrict__ b_b,
                      f16* __restrict__ G_f, f16* __restrict__ G_b) {
  const int dir = blockIdx.z;
  const float* __restrict__ Wk   = dir ? Wk_b : Wk_f;
  const float* __restrict__ bias = dir ? b_b  : b_f;
  f16* __restrict__ G = dir ? G_b : G_f;

  const int m0 = blockIdx.x * 64;
  const int n0 = blockIdx.y * 256;
  const int tid = threadIdx.x;

  __shared__ f16 Eh[64][80];
  __shared__ f16 Bh[256][80];

  #pragma unroll
  for (int s = 0; s < 4; ++s) {
    int idx = tid + s * 256;
    int r = idx >> 4, c4 = (idx & 15) * 4;
    int row = m0 + r;
    float4 ev;
    if (row < VOCAB) ev = *(const float4*)(E + (size_t)row * EMB + c4);
    else { ev.x = 0.f; ev.y = 0.f; ev.z = 0.f; ev.w = 0.f; }
    f16x4 v; v[0] = (f16)ev.x; v[1] = (f16)ev.y; v[2] = (f16)ev.z; v[3] = (f16)ev.w;
    *(f16x4*)&Eh[r][c4] = v;
  }
  #pragma unroll
  for (int s = 0; s < 32; ++s) {
    int idx = tid + s * 256;
    int k = idx >> 7, n2 = (idx & 127) * 2;
    float2 wv = *(const float2*)(Wk + (size_t)k * G4 + n0 + n2);
    Bh[n2][k]     = (f16)wv.x;
    Bh[n2 + 1][k] = (f16)wv.y;
  }
  __syncthreads();

  const int w = tid >> 6, l = tid & 63, mn = l & 15, q = l >> 4;
  f16x8 a0 = *(const f16x8*)&Eh[16 * w + mn][8 * q];
  f16x8 a1 = *(const f16x8*)&Eh[16 * w + mn][32 + 8 * q];

  f32x4 acc[16];
  #pragma unroll
  for (int nt = 0; nt < 16; ++nt) {
    f16x8 b0 = *(const f16x8*)&Bh[16 * nt + mn][8 * q];
    f16x8 b1 = *(const f16x8*)&Bh[16 * nt + mn][32 + 8 * q];
    f32x4 z = {0.f, 0.f, 0.f, 0.f};
    z = MFMA16(a0, b0, z);
    z = MFMA16(a1, b1, z);
    acc[nt] = z;
  }

  const int gA = n0 >> 7;
  #pragma unroll
  for (int nt = 0; nt < 8; ++nt) {
    int hid = 16 * nt + mn;
    float bv0 = bias[n0 + 16 * nt + mn];
    float bv1 = bias[n0 + 128 + 16 * nt + mn];
    #pragma unroll
    for (int reg = 0; reg < 4; ++reg) {
      int row = m0 + 16 * w + 4 * q + reg;
      if (row < VOCAB) {
        f16x2 v; v.x = (f16)(acc[nt][reg] + bv0); v.y = (f16)(acc[nt + 8][reg] + bv1);
        *(f16x2*)(G + (size_t)row * G4 + hid * 4 + gA) = v;
      }
    }
  }
}

// ---------------------------------------------------------------------------
// Kernel B: MFMA LSTM (R16 form — measured best, 313us). Broadcast-A:
// 4 batches per block, A[m][k]=h[m&3][k] so D row r = batch r&3. 128 blocks,
// 512 thr. Wave w owns gate cols {128g+16w+mn}; gates on ALL 512 threads via
// SEL4 from C-regs; ONE lgkm-only barrier/step; G prefetch ring depth 4;
// logit MFMAs on waves 6,7 with incremental store pointer.
// ---------------------------------------------------------------------------
__global__ __launch_bounds__(512, 1)
void lstm_mfma_kernel(const int* __restrict__ tokens,
                      const f16* __restrict__ G_f, const f16* __restrict__ G_b,
                      const float* __restrict__ Wr_f, const float* __restrict__ Wr_b,
                      const float* __restrict__ Wd, const float* __restrict__ bd,
                      float* __restrict__ Lf, float* __restrict__ Lb) {
  const int bg  = blockIdx.x;          // 0..63
  const int dir = blockIdx.y;
  const int b0  = bg * 4;
  const f16* __restrict__ G = dir ? G_b : G_f;
  const char* __restrict__ Gc = (const char*)G;
  const float* __restrict__ Wr = dir ? Wr_b : Wr_f;
  float* __restrict__ Lout = dir ? Lb : Lf;

  const int tid = threadIdx.x;
  const int w = tid >> 6;
  const int l = tid & 63;
  const int mn = l & 15;
  const int q  = l >> 4;
  const int hid = 16 * w + mn;
  const int hid8 = hid * 8;            // byte offset: hid*4 f16

  __shared__ __align__(16) f16 h_lds[2][4][160];   // [buf][batch][hid+pad]
  __shared__ int tokT[SEQ][4];                     // pre-shifted byte offsets

  #pragma unroll
  for (int s = 0; s < 4; ++s) {
    int idx = tid + s * 512;            // 2048 entries
    int t = idx >> 2, qq = idx & 3;
    tokT[t][qq] = tokens[(size_t)(b0 + qq) * SEQ + t] << 10;
  }
  if (tid < 320) ((unsigned*)&h_lds[0][0][0])[tid] = 0u;   // zero buf 0

  // B fragments: Wr[k][128g + hid], k = 32s + 8q + j  (64 VGPRs)
  f16x8 bw[4][4];
  #pragma unroll
  for (int g = 0; g < 4; ++g) {
    #pragma unroll
    for (int s = 0; s < 4; ++s) {
      f16x8 v;
      const int colv = 128 * g + hid;
      #pragma unroll
      for (int j = 0; j < 8; ++j)
        v[j] = (f16)Wr[(size_t)(32 * s + 8 * q + j) * G4 + colv];
      bw[g][s] = v;
    }
  }
  // Wd fragments on waves 6,7: tag = 16*(w-6)+mn
  f16x8 wdf0{}, wdf1{}, wdf2{}, wdf3{};
  float bdv = 0.0f;
  if (w >= 6) {
    const int tag = 16 * (w - 6) + mn;
    #pragma unroll
    for (int j = 0; j < 8; ++j) {
      wdf0[j] = (f16)Wd[(size_t)(128 * dir +  0 + 8 * q + j) * TAGS + tag];
      wdf1[j] = (f16)Wd[(size_t)(128 * dir + 32 + 8 * q + j) * TAGS + tag];
      wdf2[j] = (f16)Wd[(size_t)(128 * dir + 64 + 8 * q + j) * TAGS + tag];
      wdf3[j] = (f16)Wd[(size_t)(128 * dir + 96 + 8 * q + j) * TAGS + tag];
    }
    if (dir == 0) bdv = bd[tag];
  }

  // incremental logit store pointer (waves 6,7 / q==0 use it)
  const int t0 = dir ? (SEQ - 1) : 0;
  const int tagw = (w >= 6) ? (16 * (w - 6) + mn) : 0;
  char* lp = (char*)(Lout + ((size_t)b0 * SEQ + t0) * TAGS + tagw);
  const int ldt = dir ? -(int)(TAGS * 4) : (int)(TAGS * 4);

  float cst = 0.0f;   // cell state for (batch q, hid) — every lane
  __syncthreads();

#define TT(S) (dir ? (SEQ - 1 - (S)) : (S))

#define LOADG(S, GV) do {                                                      \
    int _tk = tokT[TT(S)][q];                                                  \
    GV = *(const uint2*)(Gc + _tk + hid8);                                     \
  } while (0)

// select element `q` (lane-var) from the 4 accum rows (= batches)
#define SEL4(V) ((q & 2) ? ((q & 1) ? V[3] : V[2]) : ((q & 1) ? V[1] : V[0]))

#define STEP(S, GV) do {                                                       \
    const int _s = (S);                                                        \
    const f16* hb = &h_lds[_s & 1][mn & 3][0];                                 \
    f16x8 a0 = *(const f16x8*)(hb      + 8 * q);                               \
    f16x8 a1 = *(const f16x8*)(hb + 32 + 8 * q);                               \
    f16x8 a2 = *(const f16x8*)(hb + 64 + 8 * q);                               \
    f16x8 a3 = *(const f16x8*)(hb + 96 + 8 * q);                               \
    f32x4 z0 = {0.f,0.f,0.f,0.f}, z1 = {0.f,0.f,0.f,0.f};                      \
    f32x4 z2 = {0.f,0.f,0.f,0.f}, z3 = {0.f,0.f,0.f,0.f};                      \
    z0 = MFMA16(a0, bw[0][0], z0); z0 = MFMA16(a1, bw[0][1], z0);              \
    z0 = MFMA16(a2, bw[0][2], z0); z0 = MFMA16(a3, bw[0][3], z0);              \
    z1 = MFMA16(a0, bw[1][0], z1); z1 = MFMA16(a1, bw[1][1], z1);              \
    z1 = MFMA16(a2, bw[1][2], z1); z1 = MFMA16(a3, bw[1][3], z1);              \
    z2 = MFMA16(a0, bw[2][0], z2); z2 = MFMA16(a1, bw[2][1], z2);              \
    z2 = MFMA16(a2, bw[2][2], z2); z2 = MFMA16(a3, bw[2][3], z2);              \
    z3 = MFMA16(a0, bw[3][0], z3); z3 = MFMA16(a1, bw[3][1], z3);              \
    z3 = MFMA16(a2, bw[3][2], z3); z3 = MFMA16(a3, bw[3][3], z3);              \
    if (w >= 6) {                                                              \
      f32x4 la = {0.f,0.f,0.f,0.f};                                            \
      la = MFMA16(a0, wdf0, la); la = MFMA16(a1, wdf1, la);                    \
      la = MFMA16(a2, wdf2, la); la = MFMA16(a3, wdf3, la);                    \
      if (q == 0) {                                                            \
        *(float*)(lp               ) = la[0] + bdv;                            \
        *(float*)(lp + SEQ*TAGS*4  ) = la[1] + bdv;                            \
        *(float*)(lp + SEQ*TAGS*8  ) = la[2] + bdv;                            \
        *(float*)(lp + SEQ*TAGS*12 ) = la[3] + bdv;                            \
      }                                                                        \
    }                                                                          \
    lp += ldt;                                                                 \
    {                                                                          \
      float zi = SEL4(z0);                                                     \
      float zf = SEL4(z1);                                                     \
      float zg = SEL4(z2);                                                     \
      float zo = SEL4(z3);                                                     \
      f16x4 gv = __builtin_bit_cast(f16x4, GV);                                \
      zi += (float)gv[0]; zf += (float)gv[1];                                  \
      zg += (float)gv[2]; zo += (float)gv[3];                                  \
      float ei = __expf(-zi);                                                  \
      float eg = __expf(fminf(2.f * zg, 30.f));                                \
      float sab = (eg - 1.f) * rcpf((1.f + ei) * (eg + 1.f));                  \
      float ef = __expf(-zf);                                                  \
      float cc = rcpf(1.f + ef) * cst + sab;                                   \
      cst = cc;                                                                \
      float eo = __expf(-zo);                                                  \
      float ec = __expf(fminf(2.f * cc, 30.f));                                \
      float hh = (ec - 1.f) * rcpf((1.f + eo) * (ec + 1.f));                   \
      h_lds[(_s + 1) & 1][q][hid] = (f16)hh;                                   \
    }                                                                          \
    asm volatile("s_waitcnt lgkmcnt(0)" ::: "memory");                         \
    __builtin_amdgcn_s_barrier();                                              \
  } while (0)

  uint2 gA, gB, gC, gD;
  LOADG(0, gA); LOADG(1, gB); LOADG(2, gC); LOADG(3, gD);

  for (int it = 0; it < SEQ / 4; ++it) {
    const int s = 4 * it;
    STEP(s + 0, gA);
    { int sc = (s + 4 < SEQ) ? s + 4 : SEQ - 1; LOADG(sc, gA); }
    STEP(s + 1, gB);
    { int sc = (s + 5 < SEQ) ? s + 5 : SEQ - 1; LOADG(sc, gB); }
    STEP(s + 2, gC);
    { int sc = (s + 6 < SEQ) ? s + 6 : SEQ - 1; LOADG(sc, gC); }
    STEP(s + 3, gD);
    { int sc = (s + 7 < SEQ) ? s + 7 : SEQ - 1; LOADG(sc, gD); }
  }
#undef STEP
#undef SEL4
#undef LOADG
#undef TT
}

// ---------------------------------------------------------------------------
// Kernel C: CRF log-likelihood (R15 form — measured best). ONE wave per
// batch, 256 blocks. Factorized exp-space scan; per-step readfirstlane
// renorm (SALU — no LDS in the chain).
// ---------------------------------------------------------------------------
__global__ __launch_bounds__(64)
void crf_kernel(const float* __restrict__ Lf,
                const float* __restrict__ Lb,
                const float* __restrict__ trans,
                const int* __restrict__ labels,
                float* __restrict__ out) {
  const int b = blockIdx.x;
  const int lane = threadIdx.x;
  const int k  = lane & 31;
  const int jh = lane >> 5;

  __shared__ float tr[TAGS * TAGS];
  __shared__ __align__(16) float e_lds[TAGS];

  for (int i = lane; i < TAGS * TAGS; i += 64) tr[i] = trans[i];
  __syncthreads();

  float wxp[16];
  #pragma unroll
  for (int i = 0; i < 16; ++i) wxp[i] = __expf(tr[(jh * 16 + i) * TAGS + k]);

  const size_t base0 = (size_t)b * SEQ * TAGS;
  float cur = Lf[base0 + k] + Lb[base0 + k];
  float beta0 = rfl(cur);
  float beta = cur - beta0;
  float S = beta0;

  float nxt = Lf[base0 + TAGS + k] + Lb[base0 + TAGS + k];

  for (int t = 1; t < SEQ; ++t) {
    float e = __expf(beta);
    if (lane < TAGS) e_lds[k] = e;
    asm volatile("s_waitcnt lgkmcnt(0)" ::: "memory");
    const float4* ep = (const float4*)&e_lds[jh * 16];
    float4 e0 = ep[0], e1 = ep[1], e2 = ep[2], e3 = ep[3];
    float d0 = e0.x * wxp[0]  + e0.y * wxp[1]  + e0.z * wxp[2]  + e0.w * wxp[3];
    float d1 = e1.x * wxp[4]  + e1.y * wxp[5]  + e1.z * wxp[6]  + e1.w * wxp[7];
    float d2 = e2.x * wxp[8]  + e2.y * wxp[9]  + e2.z * wxp[10] + e2.w * wxp[11];
    float d3 = e3.x * wxp[12] + e3.y * wxp[13] + e3.z * wxp[14] + e3.w * wxp[15];
    float dot = (d0 + d1) + (d2 + d3);
    dot += __shfl_xor(dot, 32);
    float braw = __logf(dot) + nxt;
    float bz = rfl(braw);
    beta = braw - bz;
    S += bz;
    if (t + 1 < SEQ) {
      size_t idx = base0 + (size_t)(t + 1) * TAGS + k;
      nxt = Lf[idx] + Lb[idx];
    }
  }

  float m = beta;
  #pragma unroll
  for (int off = 1; off <= 16; off <<= 1) m = fmaxf(m, __shfl_xor(m, off));
  float ex = (lane < TAGS) ? __expf(beta - m) : 0.0f;
  float s = ex;
  #pragma unroll
  for (int off = 1; off <= 32; off <<= 1) s += __shfl_xor(s, off);

  const int* lab = labels + (size_t)b * SEQ;
  float uacc = 0.f, bacc = 0.f;
  for (int t = lane; t < SEQ; t += 64) {
    int l0 = lab[t];
    size_t idx = base0 + (size_t)t * TAGS + l0;
    uacc += Lf[idx] + Lb[idx];
    if (t + 1 < SEQ) bacc += tr[l0 * TAGS + lab[t + 1]];
  }
  float red = uacc + bacc;
  #pragma unroll
  for (int off = 1; off <= 32; off <<= 1) red += __shfl_xor(red, off);

  if (lane == 0) out[b] = red - (m + __logf(s) + S);
}

// ---------------------------------------------------------------------------
// Kernel D: copy transition matrix to the second output slot.
// ---------------------------------------------------------------------------
__global__ void copy_trans_kernel(const float* __restrict__ trans,
                                  float* __restrict__ out) {
  int i = blockIdx.x * blockDim.x + threadIdx.x;
  if (i < TAGS * TAGS) out[i] = trans[i];
}

extern "C" void kernel_launch(void* const* d_in, const int* in_sizes, int n_in,
                              void* d_out, int out_size, void* d_ws, size_t ws_size,
                              hipStream_t stream) {
  const int*   inputs = (const int*)  d_in[0];
  const int*   labels = (const int*)  d_in[1];
  const float* E      = (const float*)d_in[2];
  const float* Wk_f   = (const float*)d_in[3];
  const float* Wr_f   = (const float*)d_in[4];
  const float* b_f    = (const float*)d_in[5];
  const float* Wk_b   = (const float*)d_in[6];
  const float* Wr_b   = (const float*)d_in[7];
  const float* b_b    = (const float*)d_in[8];
  const float* Wd     = (const float*)d_in[9];
  const float* bd     = (const float*)d_in[10];
  const float* trans  = (const float*)d_in[11];
  float* out = (float*)d_out;

  char* ws = (char*)d_ws;
  const size_t G_ELEMS = (size_t)VOCAB * G4;            // 25,600,512 f16 each dir
  f16* G_f = (f16*)ws;
  f16* G_b = G_f + G_ELEMS;
  float* Lfp = (float*)(ws + 2 * G_ELEMS * sizeof(f16));
  float* Lbp = Lfp + (size_t)BATCH * SEQ * TAGS;

  dim3 ggrid((VOCAB + 63) / 64, 2, 2);
  gtab_mfma_kernel<<<ggrid, 256, 0, stream>>>(E, Wk_f, b_f, Wk_b, b_b, G_f, G_b);

  lstm_mfma_kernel<<<dim3(BATCH / 4, 2), 512, 0, stream>>>(
      inputs, G_f, G_b, Wr_f, Wr_b, Wd, bd, Lfp, Lbp);

  crf_kernel<<<BATCH, 64, 0, stream>>>(Lfp, Lbp, trans, labels, out);

  copy_trans_kernel<<<(TAGS * TAGS + 255) / 256, 256, 0, stream>>>(trans, out + BATCH);
}

// Round 19
// 441.290 us; speedup vs baseline: 1.3663x; 1.1317x over previous
//
#include <hip/hip_runtime.h>
#include <hip/hip_bf16.h>
#include <cstdint>
#include <cstddef>

#define VOCAB 50001
#define EMB 64
#define HID 128
#define G4  512   // 4*HID
#define TAGS 32
#define BATCH 256
#define SEQ 512
#define LOG2E 1.44269504f

typedef _Float16 f16;
typedef _Float16 f16x2 __attribute__((ext_vector_type(2)));
typedef _Float16 f16x4 __attribute__((ext_vector_type(4)));
typedef _Float16 f16x8 __attribute__((ext_vector_type(8)));
typedef float f32x4 __attribute__((ext_vector_type(4)));

__device__ __forceinline__ float rcpf(float x) { return __builtin_amdgcn_rcpf(x); }
__device__ __forceinline__ float exp2f_(float x) { return __builtin_amdgcn_exp2f(x); }
__device__ __forceinline__ float rfl(float x) {
  return __builtin_bit_cast(float, __builtin_amdgcn_readfirstlane(__builtin_bit_cast(int, x)));
}

#define MFMA16(A, B, C) __builtin_amdgcn_mfma_f32_16x16x32_f16((A), (B), (C), 0, 0, 0)

// ---------------------------------------------------------------------------
// Kernel A: gate tables via MFMA (R15 split form). G stores LOG2-DOMAIN
// pre-activations: G[v][hid*4+gate] = (E @ Wk + b) * log2e, f16.
// ---------------------------------------------------------------------------
__global__ __launch_bounds__(256)
void gtab_mfma_kernel(const float* __restrict__ E,
                      const float* __restrict__ Wk_f, const float* __restrict__ b_f,
                      const float* __restrict__ Wk_b, const float* __restrict__ b_b,
                      f16* __restrict__ G_f, f16* __restrict__ G_b) {
  const int dir = blockIdx.z;
  const float* __restrict__ Wk   = dir ? Wk_b : Wk_f;
  const float* __restrict__ bias = dir ? b_b  : b_f;
  f16* __restrict__ G = dir ? G_b : G_f;

  const int m0 = blockIdx.x * 64;
  const int n0 = blockIdx.y * 256;
  const int tid = threadIdx.x;

  __shared__ f16 Eh[64][80];
  __shared__ f16 Bh[256][80];

  #pragma unroll
  for (int s = 0; s < 4; ++s) {
    int idx = tid + s * 256;
    int r = idx >> 4, c4 = (idx & 15) * 4;
    int row = m0 + r;
    float4 ev;
    if (row < VOCAB) ev = *(const float4*)(E + (size_t)row * EMB + c4);
    else { ev.x = 0.f; ev.y = 0.f; ev.z = 0.f; ev.w = 0.f; }
    f16x4 v; v[0] = (f16)ev.x; v[1] = (f16)ev.y; v[2] = (f16)ev.z; v[3] = (f16)ev.w;
    *(f16x4*)&Eh[r][c4] = v;
  }
  #pragma unroll
  for (int s = 0; s < 32; ++s) {
    int idx = tid + s * 256;
    int k = idx >> 7, n2 = (idx & 127) * 2;
    float2 wv = *(const float2*)(Wk + (size_t)k * G4 + n0 + n2);
    Bh[n2][k]     = (f16)wv.x;
    Bh[n2 + 1][k] = (f16)wv.y;
  }
  __syncthreads();

  const int w = tid >> 6, l = tid & 63, mn = l & 15, q = l >> 4;
  f16x8 a0 = *(const f16x8*)&Eh[16 * w + mn][8 * q];
  f16x8 a1 = *(const f16x8*)&Eh[16 * w + mn][32 + 8 * q];

  f32x4 acc[16];
  #pragma unroll
  for (int nt = 0; nt < 16; ++nt) {
    f16x8 b0 = *(const f16x8*)&Bh[16 * nt + mn][8 * q];
    f16x8 b1 = *(const f16x8*)&Bh[16 * nt + mn][32 + 8 * q];
    f32x4 z = {0.f, 0.f, 0.f, 0.f};
    z = MFMA16(a0, b0, z);
    z = MFMA16(a1, b1, z);
    acc[nt] = z;
  }

  const int gA = n0 >> 7;
  #pragma unroll
  for (int nt = 0; nt < 8; ++nt) {
    int hid = 16 * nt + mn;
    float bv0 = bias[n0 + 16 * nt + mn];
    float bv1 = bias[n0 + 128 + 16 * nt + mn];
    #pragma unroll
    for (int reg = 0; reg < 4; ++reg) {
      int row = m0 + 16 * w + 4 * q + reg;
      if (row < VOCAB) {
        f16x2 v;
        v.x = (f16)((acc[nt][reg] + bv0) * LOG2E);
        v.y = (f16)((acc[nt + 8][reg] + bv1) * LOG2E);
        *(f16x2*)(G + (size_t)row * G4 + hid * 4 + gA) = v;
      }
    }
  }
}

// ---------------------------------------------------------------------------
// Kernel B: MFMA LSTM, batch-grouped broadcast-A: A[m][k]=h[m>>2][k] so
// D row 4q+i = batch q — lane (q,mn) reads its gates directly from reg 0 of
// each quadrant (no SEL4 cndmasks). Wr fragments pre-scaled by log2e so all
// gate exponentials are bare v_exp (2^x). 128 blocks, 512 thr; wave w owns
// gate cols {128g+16w+mn}; gates on ALL 512 threads (1 set each); ONE
// lgkm-only barrier/step; G ring depth 4; logit MFMAs on waves 6,7 with
// per-lane store (batch q).
// ---------------------------------------------------------------------------
__global__ __launch_bounds__(512, 1)
void lstm_mfma_kernel(const int* __restrict__ tokens,
                      const f16* __restrict__ G_f, const f16* __restrict__ G_b,
                      const float* __restrict__ Wr_f, const float* __restrict__ Wr_b,
                      const float* __restrict__ Wd, const float* __restrict__ bd,
                      float* __restrict__ Lf, float* __restrict__ Lb) {
  const int bg  = blockIdx.x;          // 0..63
  const int dir = blockIdx.y;
  const int b0  = bg * 4;
  const f16* __restrict__ G = dir ? G_b : G_f;
  const char* __restrict__ Gc = (const char*)G;
  const float* __restrict__ Wr = dir ? Wr_b : Wr_f;
  float* __restrict__ Lout = dir ? Lb : Lf;

  const int tid = threadIdx.x;
  const int w = tid >> 6;
  const int l = tid & 63;
  const int mn = l & 15;
  const int q  = l >> 4;
  const int hid = 16 * w + mn;
  const int hid8 = hid * 8;            // byte offset: hid*4 f16

  __shared__ __align__(16) f16 h_lds[2][4][160];   // [buf][batch][hid+pad]
  __shared__ int tokT[SEQ][4];                     // pre-shifted byte offsets

  #pragma unroll
  for (int s = 0; s < 4; ++s) {
    int idx = tid + s * 512;            // 2048 entries
    int t = idx >> 2, qq = idx & 3;
    tokT[t][qq] = tokens[(size_t)(b0 + qq) * SEQ + t] << 10;
  }
  if (tid < 320) ((unsigned*)&h_lds[0][0][0])[tid] = 0u;   // zero buf 0

  // B fragments: Wr[k][128g + hid] * log2e, k = 32s + 8q + j  (64 VGPRs)
  f16x8 bw[4][4];
  #pragma unroll
  for (int g = 0; g < 4; ++g) {
    #pragma unroll
    for (int s = 0; s < 4; ++s) {
      f16x8 v;
      const int colv = 128 * g + hid;
      #pragma unroll
      for (int j = 0; j < 8; ++j)
        v[j] = (f16)(Wr[(size_t)(32 * s + 8 * q + j) * G4 + colv] * LOG2E);
      bw[g][s] = v;
    }
  }
  // Wd fragments on waves 6,7: tag = 16*(w-6)+mn  (NOT scaled — logits real)
  f16x8 wdf0{}, wdf1{}, wdf2{}, wdf3{};
  float bdv = 0.0f;
  if (w >= 6) {
    const int tag = 16 * (w - 6) + mn;
    #pragma unroll
    for (int j = 0; j < 8; ++j) {
      wdf0[j] = (f16)Wd[(size_t)(128 * dir +  0 + 8 * q + j) * TAGS + tag];
      wdf1[j] = (f16)Wd[(size_t)(128 * dir + 32 + 8 * q + j) * TAGS + tag];
      wdf2[j] = (f16)Wd[(size_t)(128 * dir + 64 + 8 * q + j) * TAGS + tag];
      wdf3[j] = (f16)Wd[(size_t)(128 * dir + 96 + 8 * q + j) * TAGS + tag];
    }
    if (dir == 0) bdv = bd[tag];
  }

  // per-lane incremental logit store pointer (waves 6,7): batch q, tag
  const int t0 = dir ? (SEQ - 1) : 0;
  const int tagw = (w >= 6) ? (16 * (w - 6) + mn) : 0;
  char* lp = (char*)(Lout + ((size_t)(b0 + q) * SEQ + t0) * TAGS + tagw);
  const int ldt = dir ? -(int)(TAGS * 4) : (int)(TAGS * 4);

  float cst = 0.0f;   // cell state for (batch q, hid) — every lane
  __syncthreads();

#define TT(S) (dir ? (SEQ - 1 - (S)) : (S))

#define LOADG(S, GV) do {                                                      \
    int _tk = tokT[TT(S)][q];                                                  \
    GV = *(const uint2*)(Gc + _tk + hid8);                                     \
  } while (0)

#define STEP(S, GV) do {                                                       \
    const int _s = (S);                                                        \
    const f16* hb = &h_lds[_s & 1][mn >> 2][0];                                \
    f16x8 a0 = *(const f16x8*)(hb      + 8 * q);                               \
    f16x8 a1 = *(const f16x8*)(hb + 32 + 8 * q);                               \
    f16x8 a2 = *(const f16x8*)(hb + 64 + 8 * q);                               \
    f16x8 a3 = *(const f16x8*)(hb + 96 + 8 * q);                               \
    f32x4 z0 = {0.f,0.f,0.f,0.f}, z1 = {0.f,0.f,0.f,0.f};                      \
    f32x4 z2 = {0.f,0.f,0.f,0.f}, z3 = {0.f,0.f,0.f,0.f};                      \
    z0 = MFMA16(a0, bw[0][0], z0); z0 = MFMA16(a1, bw[0][1], z0);              \
    z0 = MFMA16(a2, bw[0][2], z0); z0 = MFMA16(a3, bw[0][3], z0);              \
    z1 = MFMA16(a0, bw[1][0], z1); z1 = MFMA16(a1, bw[1][1], z1);              \
    z1 = MFMA16(a2, bw[1][2], z1); z1 = MFMA16(a3, bw[1][3], z1);              \
    z2 = MFMA16(a0, bw[2][0], z2); z2 = MFMA16(a1, bw[2][1], z2);              \
    z2 = MFMA16(a2, bw[2][2], z2); z2 = MFMA16(a3, bw[2][3], z2);              \
    z3 = MFMA16(a0, bw[3][0], z3); z3 = MFMA16(a1, bw[3][1], z3);              \
    z3 = MFMA16(a2, bw[3][2], z3); z3 = MFMA16(a3, bw[3][3], z3);              \
    if (w >= 6) {                                                              \
      f32x4 la = {0.f,0.f,0.f,0.f};                                            \
      la = MFMA16(a0, wdf0, la); la = MFMA16(a1, wdf1, la);                    \
      la = MFMA16(a2, wdf2, la); la = MFMA16(a3, wdf3, la);                    \
      *(float*)(lp) = la[0] + bdv;                                             \
    }                                                                          \
    lp += ldt;                                                                 \
    {                                                                          \
      f16x4 gv = __builtin_bit_cast(f16x4, GV);                                \
      float zi = z0[0] + (float)gv[0];   /* log2-domain */                     \
      float zf = z1[0] + (float)gv[1];                                         \
      float zg = z2[0] + (float)gv[2];                                         \
      float zo = z3[0] + (float)gv[3];                                         \
      float ei = exp2f_(-zi);                                                  \
      float eg = exp2f_(fminf(zg + zg, 43.f));                                 \
      float sab = (eg - 1.f) * rcpf((1.f + ei) * (eg + 1.f));                  \
      float ef = exp2f_(-zf);                                                  \
      float cc = rcpf(1.f + ef) * cst + sab;                                   \
      cst = cc;                                                                \
      float eo = exp2f_(-zo);                                                  \
      float ec = exp2f_(fminf(cc * (2.f * LOG2E), 43.f));                      \
      float hh = (ec - 1.f) * rcpf((1.f + eo) * (ec + 1.f));                   \
      h_lds[(_s + 1) & 1][q][hid] = (f16)hh;                                   \
    }                                                                          \
    asm volatile("s_waitcnt lgkmcnt(0)" ::: "memory");                         \
    __builtin_amdgcn_s_barrier();                                              \
  } while (0)

  uint2 gA, gB, gC, gD;
  LOADG(0, gA); LOADG(1, gB); LOADG(2, gC); LOADG(3, gD);

  for (int it = 0; it < SEQ / 4; ++it) {
    const int s = 4 * it;
    STEP(s + 0, gA);
    { int sc = (s + 4 < SEQ) ? s + 4 : SEQ - 1; LOADG(sc, gA); }
    STEP(s + 1, gB);
    { int sc = (s + 5 < SEQ) ? s + 5 : SEQ - 1; LOADG(sc, gB); }
    STEP(s + 2, gC);
    { int sc = (s + 6 < SEQ) ? s + 6 : SEQ - 1; LOADG(sc, gC); }
    STEP(s + 3, gD);
    { int sc = (s + 7 < SEQ) ? s + 7 : SEQ - 1; LOADG(sc, gD); }
  }
#undef STEP
#undef LOADG
#undef TT
}

// ---------------------------------------------------------------------------
// Kernel C: CRF log-likelihood (R15 form). ONE wave per batch, 256 blocks.
// Factorized exp-space scan; per-step readfirstlane renorm.
// ---------------------------------------------------------------------------
__global__ __launch_bounds__(64)
void crf_kernel(const float* __restrict__ Lf,
                const float* __restrict__ Lb,
                const float* __restrict__ trans,
                const int* __restrict__ labels,
                float* __restrict__ out) {
  const int b = blockIdx.x;
  const int lane = threadIdx.x;
  const int k  = lane & 31;
  const int jh = lane >> 5;

  __shared__ float tr[TAGS * TAGS];
  __shared__ __align__(16) float e_lds[TAGS];

  for (int i = lane; i < TAGS * TAGS; i += 64) tr[i] = trans[i];
  __syncthreads();

  float wxp[16];
  #pragma unroll
  for (int i = 0; i < 16; ++i) wxp[i] = __expf(tr[(jh * 16 + i) * TAGS + k]);

  const size_t base0 = (size_t)b * SEQ * TAGS;
  float cur = Lf[base0 + k] + Lb[base0 + k];
  float beta0 = rfl(cur);
  float beta = cur - beta0;
  float S = beta0;

  float nxt = Lf[base0 + TAGS + k] + Lb[base0 + TAGS + k];

  for (int t = 1; t < SEQ; ++t) {
    float e = __expf(beta);
    if (lane < TAGS) e_lds[k] = e;
    asm volatile("s_waitcnt lgkmcnt(0)" ::: "memory");
    const float4* ep = (const float4*)&e_lds[jh * 16];
    float4 e0 = ep[0], e1 = ep[1], e2 = ep[2], e3 = ep[3];
    float d0 = e0.x * wxp[0]  + e0.y * wxp[1]  + e0.z * wxp[2]  + e0.w * wxp[3];
    float d1 = e1.x * wxp[4]  + e1.y * wxp[5]  + e1.z * wxp[6]  + e1.w * wxp[7];
    float d2 = e2.x * wxp[8]  + e2.y * wxp[9]  + e2.z * wxp[10] + e2.w * wxp[11];
    float d3 = e3.x * wxp[12] + e3.y * wxp[13] + e3.z * wxp[14] + e3.w * wxp[15];
    float dot = (d0 + d1) + (d2 + d3);
    dot += __shfl_xor(dot, 32);
    float braw = __logf(dot) + nxt;
    float bz = rfl(braw);
    beta = braw - bz;
    S += bz;
    if (t + 1 < SEQ) {
      size_t idx = base0 + (size_t)(t + 1) * TAGS + k;
      nxt = Lf[idx] + Lb[idx];
    }
  }

  float m = beta;
  #pragma unroll
  for (int off = 1; off <= 16; off <<= 1) m = fmaxf(m, __shfl_xor(m, off));
  float ex = (lane < TAGS) ? __expf(beta - m) : 0.0f;
  float s = ex;
  #pragma unroll
  for (int off = 1; off <= 32; off <<= 1) s += __shfl_xor(s, off);

  const int* lab = labels + (size_t)b * SEQ;
  float uacc = 0.f, bacc = 0.f;
  for (int t = lane; t < SEQ; t += 64) {
    int l0 = lab[t];
    size_t idx = base0 + (size_t)t * TAGS + l0;
    uacc += Lf[idx] + Lb[idx];
    if (t + 1 < SEQ) bacc += tr[l0 * TAGS + lab[t + 1]];
  }
  float red = uacc + bacc;
  #pragma unroll
  for (int off = 1; off <= 32; off <<= 1) red += __shfl_xor(red, off);

  if (lane == 0) out[b] = red - (m + __logf(s) + S);
}

// ---------------------------------------------------------------------------
// Kernel D: copy transition matrix to the second output slot.
// ---------------------------------------------------------------------------
__global__ void copy_trans_kernel(const float* __restrict__ trans,
                                  float* __restrict__ out) {
  int i = blockIdx.x * blockDim.x + threadIdx.x;
  if (i < TAGS * TAGS) out[i] = trans[i];
}

extern "C" void kernel_launch(void* const* d_in, const int* in_sizes, int n_in,
                              void* d_out, int out_size, void* d_ws, size_t ws_size,
                              hipStream_t stream) {
  const int*   inputs = (const int*)  d_in[0];
  const int*   labels = (const int*)  d_in[1];
  const float* E      = (const float*)d_in[2];
  const float* Wk_f   = (const float*)d_in[3];
  const float* Wr_f   = (const float*)d_in[4];
  const float* b_f    = (const float*)d_in[5];
  const float* Wk_b   = (const float*)d_in[6];
  const float* Wr_b   = (const float*)d_in[7];
  const float* b_b    = (const float*)d_in[8];
  const float* Wd     = (const float*)d_in[9];
  const float* bd     = (const float*)d_in[10];
  const float* trans  = (const float*)d_in[11];
  float* out = (float*)d_out;

  char* ws = (char*)d_ws;
  const size_t G_ELEMS = (size_t)VOCAB * G4;            // 25,600,512 f16 each dir
  f16* G_f = (f16*)ws;
  f16* G_b = G_f + G_ELEMS;
  float* Lfp = (float*)(ws + 2 * G_ELEMS * sizeof(f16));
  float* Lbp = Lfp + (size_t)BATCH * SEQ * TAGS;

  dim3 ggrid((VOCAB + 63) / 64, 2, 2);
  gtab_mfma_kernel<<<ggrid, 256, 0, stream>>>(E, Wk_f, b_f, Wk_b, b_b, G_f, G_b);

  lstm_mfma_kernel<<<dim3(BATCH / 4, 2), 512, 0, stream>>>(
      inputs, G_f, G_b, Wr_f, Wr_b, Wd, bd, Lfp, Lbp);

  crf_kernel<<<BATCH, 64, 0, stream>>>(Lfp, Lbp, trans, labels, out);

  copy_trans_kernel<<<(TAGS * TAGS + 255) / 256, 256, 0, stream>>>(trans, out + BATCH);
}